// Round 1
// baseline (94.242 us; speedup 1.0000x reference)
//
#include <hip/hip_runtime.h>

#define NF   784
#define ZD   64
#define BXN  256
#define BZN  4096
#define KDIM 3136    // 4*NF

typedef __attribute__((ext_vector_type(8))) short bf16x8;
typedef __attribute__((ext_vector_type(4))) float f32x4;

__device__ __forceinline__ unsigned short f2bf(float f) {
  unsigned u = __float_as_uint(f);
  u += 0x7fff + ((u >> 16) & 1);   // round-to-nearest-even
  return (unsigned short)(u >> 16);
}

// ---------------- Kernel 1: A-matrix (256 x 3136) bf16 ----------------
// A[b][4j+0..3] = [(1-xt)*x, xt*x, (1-xt)*(1-x), xt*(1-x)],  xt = x[b, tree[j]]
__global__ __launch_bounds__(256) void build_a(const float* __restrict__ x,
                                               const int* __restrict__ tree,
                                               unsigned short* __restrict__ Amat) {
  int j = blockIdx.x * 256 + threadIdx.x;
  int b = blockIdx.y;
  if (j >= NF) return;
  float xb = x[b * NF + j];
  int idx = tree[j];
  int gidx = idx < 0 ? idx + NF : idx;   // JAX negative-index wrap
  float xt = x[b * NF + gidx];
  ushort4 v;
  v.x = f2bf((1.f - xt) * xb);
  v.y = f2bf(xt * xb);
  v.z = f2bf((1.f - xt) * (1.f - xb));
  v.w = f2bf(xt * (1.f - xb));
  *(ushort4*)&Amat[(size_t)b * KDIM + 4 * j] = v;
}

// ---------------- Kernel 2: logits + log-sigmoid -> B-matrix (4096 x 3136) bf16
// B[i][4j+0..3] = [ls0, ls1, lsn0, lsn1] where l1 = z[i]·W[:,2j+1]+b, l0 = root? l1 : z[i]·W[:,2j]+b
// grid: 512 blocks = 256 row-blocks (16 z-rows each) x 2 j-halves, 256 thr
__global__ __launch_bounds__(256) void build_b(const float* __restrict__ z,
                                               const float* __restrict__ W,
                                               const float* __restrict__ bias,
                                               const int* __restrict__ tree,
                                               unsigned short* __restrict__ Bmat) {
  __shared__ float zs[16][64];
  int bx = blockIdx.x;
  int rb = bx >> 1, h = bx & 1;
  int i0 = rb * 16;
  int tid = threadIdx.x;
  {
    int r = tid >> 4, c = (tid & 15) * 4;
    *(float4*)&zs[r][c] = *(const float4*)&z[(size_t)(i0 + r) * ZD + c];
  }
  __syncthreads();
  const float2* W2 = (const float2*)W;     // W2[k*784 + j] = (W[k][2j], W[k][2j+1])
  const float2* B2 = (const float2*)bias;
  for (int jj = 0; jj < 2; ++jj) {
    int jl = jj * 256 + tid;
    if (jl >= 392) break;                  // no syncs below: divergence-safe
    int j = h * 392 + jl;
    float acc0[16], acc1[16];
#pragma unroll
    for (int r = 0; r < 16; ++r) { acc0[r] = 0.f; acc1[r] = 0.f; }
#pragma unroll 4
    for (int k4 = 0; k4 < 16; ++k4) {
      float2 w0 = W2[(k4 * 4 + 0) * NF + j];
      float2 w1 = W2[(k4 * 4 + 1) * NF + j];
      float2 w2 = W2[(k4 * 4 + 2) * NF + j];
      float2 w3 = W2[(k4 * 4 + 3) * NF + j];
#pragma unroll
      for (int r = 0; r < 16; ++r) {
        float4 zv = *(const float4*)&zs[r][k4 * 4];  // LDS broadcast (uniform addr)
        acc0[r] += zv.x * w0.x + zv.y * w1.x + zv.z * w2.x + zv.w * w3.x;
        acc1[r] += zv.x * w0.y + zv.y * w1.y + zv.z * w2.y + zv.w * w3.y;
      }
    }
    float2 bb = B2[j];
    bool root = (tree[j] == -1);
#pragma unroll
    for (int r = 0; r < 16; ++r) {
      float l1 = acc1[r] + bb.y;
      float l0 = root ? l1 : (acc0[r] + bb.x);
      // logsig(v) = v>=0 ? -log1p(e^-v) : v - log1p(e^v);  logsig(-v) = logsig(v) - v
      float e0 = __expf(-fabsf(l0)); float sp0 = log1pf(e0);
      float ls0 = (l0 >= 0.f) ? -sp0 : l0 - sp0;
      float e1 = __expf(-fabsf(l1)); float sp1 = log1pf(e1);
      float ls1 = (l1 >= 0.f) ? -sp1 : l1 - sp1;
      ushort4 v;
      v.x = f2bf(ls0);
      v.y = f2bf(ls1);
      v.z = f2bf(ls0 - l0);
      v.w = f2bf(ls1 - l1);
      *(ushort4*)&Bmat[(size_t)(i0 + r) * KDIM + 4 * j] = v;
    }
  }
}

// ---------------- Kernel 3: GEMM  out[b,i] += Σ_k A[b,k]*B[i,k] ----------------
// M=256 (b), N=4096 (i), K=3136. 64x64 tiles, 4 waves, 2-way K-split, atomicAdd.
#define LDSPAD 48   // row stride in shorts (96B): 4-way instead of 8-way conflict
__global__ __launch_bounds__(256) void gemm_k(const unsigned short* __restrict__ Amat,
                                              const unsigned short* __restrict__ Bmat,
                                              float* __restrict__ out) {
  __shared__ unsigned short As[64][LDSPAD];
  __shared__ unsigned short Bs[64][LDSPAD];
  int bid = blockIdx.x;
  int s  = bid & 1;          // K-split half
  int nt = (bid >> 1) & 63;  // N tile
  int mt = bid >> 7;         // M tile
  int m0 = mt * 64, n0 = nt * 64;
  int tid = threadIdx.x;
  int w = tid >> 6, lane = tid & 63;

  f32x4 acc[4];
#pragma unroll
  for (int t = 0; t < 4; ++t) acc[t] = (f32x4){0.f, 0.f, 0.f, 0.f};

  int srow = tid >> 2, scol = (tid & 3) * 8;          // staging: 64 rows x 32 k
  const unsigned short* Ag = Amat + (size_t)(m0 + srow) * KDIM + scol;
  const unsigned short* Bg = Bmat + (size_t)(n0 + srow) * KDIM + scol;

  int fr = lane & 15, kq = (lane >> 4) * 8;           // fragment row / k-offset

  int kt0 = s * 49, kt1 = kt0 + 49;                   // 98 K-steps split 49/49
  for (int kt = kt0; kt < kt1; ++kt) {
    int k0 = kt * 32;
    *(float4*)&As[srow][scol] = *(const float4*)(Ag + k0);
    *(float4*)&Bs[srow][scol] = *(const float4*)(Bg + k0);
    __syncthreads();
    bf16x8 af = *(bf16x8*)&As[w * 16 + fr][kq];
#pragma unroll
    for (int t = 0; t < 4; ++t) {
      bf16x8 bf = *(bf16x8*)&Bs[t * 16 + fr][kq];
      acc[t] = __builtin_amdgcn_mfma_f32_16x16x32_bf16(af, bf, acc[t], 0, 0, 0);
    }
    __syncthreads();
  }
  // C/D layout: col = lane&15, row = (lane>>4)*4 + reg   [m89 verified]
  int col = lane & 15, rq = (lane >> 4) * 4;
#pragma unroll
  for (int t = 0; t < 4; ++t) {
#pragma unroll
    for (int r = 0; r < 4; ++r) {
      int m = m0 + w * 16 + rq + r;
      int n = n0 + t * 16 + col;
      atomicAdd(&out[(size_t)m * BZN + n], acc[t][r]);
    }
  }
}

extern "C" void kernel_launch(void* const* d_in, const int* in_sizes, int n_in,
                              void* d_out, int out_size, void* d_ws, size_t ws_size,
                              hipStream_t stream) {
  const float* x    = (const float*)d_in[0];
  const float* z    = (const float*)d_in[1];
  const float* W    = (const float*)d_in[2];
  const float* bias = (const float*)d_in[3];
  const int*   tree = (const int*)d_in[4];
  float* out = (float*)d_out;

  unsigned short* Amat = (unsigned short*)d_ws;                       // 256*3136*2 = 1,605,632 B
  unsigned short* Bmat = (unsigned short*)((char*)d_ws + 1605632);    // 4096*3136*2 = 25,690,112 B

  hipMemsetAsync(d_out, 0, (size_t)out_size * sizeof(float), stream);
  build_a<<<dim3((NF + 255) / 256, BXN), 256, 0, stream>>>(x, tree, Amat);
  build_b<<<dim3(512), 256, 0, stream>>>(z, W, bias, tree, Bmat);
  gemm_k<<<dim3(512), 256, 0, stream>>>(Amat, Bmat, out);
}

// Round 2
// 70.774 us; speedup vs baseline: 1.3316x; 1.3316x over previous
//
#include <hip/hip_runtime.h>

#define NF   784
#define ZD   64
#define BXN  256
#define BZN  4096
#define KDIM 3136    // 4*NF
#define LCOL 1568    // 2*NF logit columns

typedef __attribute__((ext_vector_type(8))) short bf16x8;
typedef __attribute__((ext_vector_type(4))) float f32x4;
typedef __attribute__((ext_vector_type(8))) unsigned short ushort8;

__device__ __forceinline__ unsigned short f2bf(float f) {
  unsigned u = __float_as_uint(f);
  u += 0x7fff + ((u >> 16) & 1);   // round-to-nearest-even
  return (unsigned short)(u >> 16);
}

// ---------------- Kernel 1: prep (fused) ----------------
// blocks [0,1024):    build A-matrix (256 x 3136 bf16)
// blocks [1024,1280): z (4096x64 f32) -> zb bf16
// blocks [1280,1378): W (64x1568 f32) -> Wt (1568x64 bf16, transposed)
__global__ __launch_bounds__(256) void prep(const float* __restrict__ x,
                                            const float* __restrict__ z,
                                            const float* __restrict__ W,
                                            const int* __restrict__ tree,
                                            unsigned short* __restrict__ Amat,
                                            unsigned short* __restrict__ zb,
                                            unsigned short* __restrict__ Wt) {
  int bid = blockIdx.x, tid = threadIdx.x;
  if (bid < 1024) {                       // ---- build_a
    int b = bid >> 2;
    int j = (bid & 3) * 256 + tid;
    if (j >= NF) return;
    float xb = x[b * NF + j];
    int idx = tree[j];
    int gidx = idx < 0 ? idx + NF : idx;  // JAX negative-index wrap
    float xt = x[b * NF + gidx];
    ushort4 v;
    v.x = f2bf((1.f - xt) * xb);
    v.y = f2bf(xt * xb);
    v.z = f2bf((1.f - xt) * (1.f - xb));
    v.w = f2bf(xt * (1.f - xb));
    *(ushort4*)&Amat[(size_t)b * KDIM + 4 * j] = v;
  } else if (bid < 1280) {                // ---- z -> bf16
    int t = (bid - 1024) * 256 + tid;     // 0..65535, 4 elems each
    float4 v = *(const float4*)&z[t * 4];
    ushort4 o = { f2bf(v.x), f2bf(v.y), f2bf(v.z), f2bf(v.w) };
    *(ushort4*)&zb[t * 4] = o;
  } else {                                // ---- W -> Wt (transpose)
    int t = (bid - 1280) * 256 + tid;     // 0..25087
    int c = t >> 4, k0 = (t & 15) * 4;    // c<1568, k0<64
    ushort4 o;
    o.x = f2bf(W[(k0 + 0) * LCOL + c]);
    o.y = f2bf(W[(k0 + 1) * LCOL + c]);
    o.z = f2bf(W[(k0 + 2) * LCOL + c]);
    o.w = f2bf(W[(k0 + 3) * LCOL + c]);
    *(ushort4*)&Wt[c * 64 + k0] = o;
  }
}

// ---------------- Kernel 2: logits via MFMA + log-sigmoid -> B-matrix ----------------
// D = Wt(M=1568 logit cols) x zb(N=4096 z rows), K=64 -> 2 MFMAs, no LDS.
// Lane layout: D col = lane&15 (z-row), D rows = (lane>>4)*4+reg (4 consecutive
// logit cols = two (l0,l1) pairs) -> lane-local epilogue, one 16B store.
__global__ __launch_bounds__(256) void build_b(const unsigned short* __restrict__ zb,
                                               const unsigned short* __restrict__ Wt,
                                               const float* __restrict__ bias,
                                               const int* __restrict__ tree,
                                               unsigned short* __restrict__ Bmat) {
  int tid = threadIdx.x;
  int w = tid >> 6, lane = tid & 63;
  int job = blockIdx.x * 4 + w;           // 25088 jobs = 256 i-groups x 98 c-groups
  int ig = job / 98;
  int cg = job - ig * 98;
  int i0 = ig * 16, c0 = cg * 16;
  int fr = lane & 15, kq = (lane >> 4) * 8;

  const unsigned short* WtP = Wt + (c0 + fr) * 64 + kq;
  const unsigned short* zbP = zb + (size_t)(i0 + fr) * 64 + kq;
  bf16x8 a0 = *(const bf16x8*)(WtP);
  bf16x8 a1 = *(const bf16x8*)(WtP + 32);
  bf16x8 b0 = *(const bf16x8*)(zbP);
  bf16x8 b1 = *(const bf16x8*)(zbP + 32);
  f32x4 acc = (f32x4){0.f, 0.f, 0.f, 0.f};
  acc = __builtin_amdgcn_mfma_f32_16x16x32_bf16(a0, b0, acc, 0, 0, 0);
  acc = __builtin_amdgcn_mfma_f32_16x16x32_bf16(a1, b1, acc, 0, 0, 0);

  int row = i0 + fr;                       // z-row (D col = lane&15)
  int cb = c0 + (lane >> 4) * 4;           // logit col base (D row = (lane>>4)*4+reg)
  float4 b4 = *(const float4*)&bias[cb];
  int2 tr2 = *(const int2*)&tree[cb >> 1]; // tree[j0], tree[j0+1]
  float bb[4] = { b4.x, b4.y, b4.z, b4.w };
  int tt[2] = { tr2.x, tr2.y };
  ushort8 v;
#pragma unroll
  for (int p = 0; p < 2; ++p) {
    float l1 = acc[2 * p + 1] + bb[2 * p + 1];
    float l0 = (tt[p] == -1) ? l1 : (acc[2 * p] + bb[2 * p]);
    // logsig(v) = v>=0 ? -log(1+e^-v) : v - log(1+e^v);  logsig(-v) = logsig(v) - v
    float e0 = __expf(-fabsf(l0)); float sp0 = __logf(1.f + e0);
    float ls0 = (l0 >= 0.f) ? -sp0 : l0 - sp0;
    float e1 = __expf(-fabsf(l1)); float sp1 = __logf(1.f + e1);
    float ls1 = (l1 >= 0.f) ? -sp1 : l1 - sp1;
    v[4 * p + 0] = f2bf(ls0);
    v[4 * p + 1] = f2bf(ls1);
    v[4 * p + 2] = f2bf(ls0 - l0);
    v[4 * p + 3] = f2bf(ls1 - l1);
  }
  *(ushort8*)&Bmat[(size_t)row * KDIM + cb * 2] = v;   // 16B, aligned (cb%4==0)
}

// ---------------- Kernel 3: GEMM out[b,i] += A[256xK] . B[4096xK]^T ----------------
// Tile 256m x 64n (ONE m-pass: Bmat read exactly once), BK=32, 8-way K-split.
// 4 waves, each 64m x 64n = 16 MFMA per step. LDS pitch 40 shorts -> 2-way (free).
#define LP 40
__global__ __launch_bounds__(256) void gemm2(const unsigned short* __restrict__ Amat,
                                             const unsigned short* __restrict__ Bmat,
                                             float* __restrict__ out) {
  __shared__ unsigned short As[256][LP];   // 20480 B
  __shared__ unsigned short Bs[64][LP];    //  5120 B
  int bid = blockIdx.x;                    // 512 = 64 n-tiles x 8 k-splits
  int s = bid & 7, nt = bid >> 3;
  int n0 = nt * 64;
  int kt0 = s * 12 + (s < 2 ? s : 2);      // 98 = 13+13+12*6
  int nsteps = (s < 2) ? 13 : 12;
  int tid = threadIdx.x;
  int w = tid >> 6, lane = tid & 63;
  int srow = tid >> 2, scol = (tid & 3) * 8;
  const unsigned short* Ag = Amat + (size_t)srow * KDIM + scol;
  const unsigned short* Bg = Bmat + (size_t)(n0 + srow) * KDIM + scol;
  int fr = lane & 15, kq = (lane >> 4) * 8;

  f32x4 acc[4][4];
#pragma unroll
  for (int m = 0; m < 4; ++m)
#pragma unroll
    for (int n = 0; n < 4; ++n) acc[m][n] = (f32x4){0.f, 0.f, 0.f, 0.f};

  for (int kt = kt0; kt < kt0 + nsteps; ++kt) {
    int k0 = kt * 32;
#pragma unroll
    for (int q = 0; q < 4; ++q)
      *(float4*)&As[srow + q * 64][scol] = *(const float4*)(Ag + (size_t)q * 64 * KDIM + k0);
    *(float4*)&Bs[srow][scol] = *(const float4*)(Bg + k0);
    __syncthreads();
    bf16x8 a[4], b[4];
#pragma unroll
    for (int m = 0; m < 4; ++m) a[m] = *(const bf16x8*)&As[w * 64 + m * 16 + fr][kq];
#pragma unroll
    for (int n = 0; n < 4; ++n) b[n] = *(const bf16x8*)&Bs[n * 16 + fr][kq];
#pragma unroll
    for (int m = 0; m < 4; ++m)
#pragma unroll
      for (int n = 0; n < 4; ++n)
        acc[m][n] = __builtin_amdgcn_mfma_f32_16x16x32_bf16(a[m], b[n], acc[m][n], 0, 0, 0);
    __syncthreads();
  }
  // C/D: col = lane&15 (n), row = (lane>>4)*4 + reg (m)
  int col = lane & 15, rq = (lane >> 4) * 4;
#pragma unroll
  for (int m = 0; m < 4; ++m)
#pragma unroll
    for (int n = 0; n < 4; ++n)
#pragma unroll
      for (int r = 0; r < 4; ++r) {
        int mm = w * 64 + m * 16 + rq + r;
        int nn = n0 + n * 16 + col;
        atomicAdd(&out[(size_t)mm * BZN + nn], acc[m][n][r]);
      }
}

extern "C" void kernel_launch(void* const* d_in, const int* in_sizes, int n_in,
                              void* d_out, int out_size, void* d_ws, size_t ws_size,
                              hipStream_t stream) {
  const float* x    = (const float*)d_in[0];
  const float* z    = (const float*)d_in[1];
  const float* W    = (const float*)d_in[2];
  const float* bias = (const float*)d_in[3];
  const int*   tree = (const int*)d_in[4];
  float* out = (float*)d_out;

  unsigned short* Amat = (unsigned short*)d_ws;                        // 1,605,632 B
  unsigned short* Bmat = (unsigned short*)((char*)d_ws + 1605632);     // 25,690,112 B
  unsigned short* zb   = (unsigned short*)((char*)d_ws + 27295744);    //   524,288 B
  unsigned short* Wt   = (unsigned short*)((char*)d_ws + 27820032);    //   200,704 B

  hipMemsetAsync(d_out, 0, (size_t)out_size * sizeof(float), stream);
  prep<<<dim3(1378), 256, 0, stream>>>(x, z, W, tree, Amat, zb, Wt);
  build_b<<<dim3(6272), 256, 0, stream>>>(zb, Wt, bias, tree, Bmat);
  gemm2<<<dim3(512), 256, 0, stream>>>(Amat, Bmat, out);
}

// Round 3
// 66.937 us; speedup vs baseline: 1.4079x; 1.0573x over previous
//
#include <hip/hip_runtime.h>

#define NF   784
#define ZD   64
#define BXN  256
#define BZN  4096
#define KDIM 3136    // 4*NF
#define LCOL 1568    // 2*NF logit columns

typedef __attribute__((ext_vector_type(8))) short bf16x8;
typedef __attribute__((ext_vector_type(4))) float f32x4;
typedef __attribute__((ext_vector_type(8))) unsigned short ushort8;

__device__ __forceinline__ unsigned short f2bf(float f) {
  unsigned u = __float_as_uint(f);
  u += 0x7fff + ((u >> 16) & 1);   // round-to-nearest-even
  return (unsigned short)(u >> 16);
}

// ---------------- Kernel 1: prep (fused) ----------------
// blocks [0,1024):     build A-matrix (256 x 3136 bf16)
// blocks [1024,1280):  z (4096x64 f32) -> zb bf16
// blocks [1280,1378):  W (64x1568 f32) -> Wt (1568x64 bf16, transposed)
// blocks [1378,2402):  zero d_out (4 MB, float4 stores) -- replaces 44us rocclr fill
__global__ __launch_bounds__(256) void prep(const float* __restrict__ x,
                                            const float* __restrict__ z,
                                            const float* __restrict__ W,
                                            const int* __restrict__ tree,
                                            unsigned short* __restrict__ Amat,
                                            unsigned short* __restrict__ zb,
                                            unsigned short* __restrict__ Wt,
                                            float* __restrict__ out) {
  int bid = blockIdx.x, tid = threadIdx.x;
  if (bid < 1024) {                       // ---- build_a
    int b = bid >> 2;
    int j = (bid & 3) * 256 + tid;
    if (j >= NF) return;
    float xb = x[b * NF + j];
    int idx = tree[j];
    int gidx = idx < 0 ? idx + NF : idx;  // JAX negative-index wrap
    float xt = x[b * NF + gidx];
    ushort4 v;
    v.x = f2bf((1.f - xt) * xb);
    v.y = f2bf(xt * xb);
    v.z = f2bf((1.f - xt) * (1.f - xb));
    v.w = f2bf(xt * (1.f - xb));
    *(ushort4*)&Amat[(size_t)b * KDIM + 4 * j] = v;
  } else if (bid < 1280) {                // ---- z -> bf16
    int t = (bid - 1024) * 256 + tid;     // 0..65535, 4 elems each
    float4 v = *(const float4*)&z[t * 4];
    ushort4 o = { f2bf(v.x), f2bf(v.y), f2bf(v.z), f2bf(v.w) };
    *(ushort4*)&zb[t * 4] = o;
  } else if (bid < 1378) {                // ---- W -> Wt (transpose)
    int t = (bid - 1280) * 256 + tid;     // 0..25087
    int c = t >> 4, k0 = (t & 15) * 4;    // c<1568, k0<64
    ushort4 o;
    o.x = f2bf(W[(k0 + 0) * LCOL + c]);
    o.y = f2bf(W[(k0 + 1) * LCOL + c]);
    o.z = f2bf(W[(k0 + 2) * LCOL + c]);
    o.w = f2bf(W[(k0 + 3) * LCOL + c]);
    *(ushort4*)&Wt[c * 64 + k0] = o;
  } else {                                // ---- zero d_out
    int t = (bid - 1378) * 256 + tid;     // 1024 blocks * 1024 floats = 1M floats
    *(float4*)&out[t * 4] = (float4){0.f, 0.f, 0.f, 0.f};
  }
}

// ---------------- Kernel 2: logits via MFMA + log-sigmoid -> B-matrix ----------------
// D = Wt(M=1568 logit cols) x zb(N=4096 z rows), K=64 -> 2 MFMAs, no LDS.
// Lane layout: D col = lane&15 (z-row), D rows = (lane>>4)*4+reg (4 consecutive
// logit cols = two (l0,l1) pairs) -> lane-local epilogue, one 16B store.
__global__ __launch_bounds__(256) void build_b(const unsigned short* __restrict__ zb,
                                               const unsigned short* __restrict__ Wt,
                                               const float* __restrict__ bias,
                                               const int* __restrict__ tree,
                                               unsigned short* __restrict__ Bmat) {
  int tid = threadIdx.x;
  int w = tid >> 6, lane = tid & 63;
  int job = blockIdx.x * 4 + w;           // 25088 jobs = 256 i-groups x 98 c-groups
  int ig = job / 98;
  int cg = job - ig * 98;
  int i0 = ig * 16, c0 = cg * 16;
  int fr = lane & 15, kq = (lane >> 4) * 8;

  const unsigned short* WtP = Wt + (c0 + fr) * 64 + kq;
  const unsigned short* zbP = zb + (size_t)(i0 + fr) * 64 + kq;
  bf16x8 a0 = *(const bf16x8*)(WtP);
  bf16x8 a1 = *(const bf16x8*)(WtP + 32);
  bf16x8 b0 = *(const bf16x8*)(zbP);
  bf16x8 b1 = *(const bf16x8*)(zbP + 32);
  f32x4 acc = (f32x4){0.f, 0.f, 0.f, 0.f};
  acc = __builtin_amdgcn_mfma_f32_16x16x32_bf16(a0, b0, acc, 0, 0, 0);
  acc = __builtin_amdgcn_mfma_f32_16x16x32_bf16(a1, b1, acc, 0, 0, 0);

  int row = i0 + fr;                       // z-row (D col = lane&15)
  int cb = c0 + (lane >> 4) * 4;           // logit col base (D row = (lane>>4)*4+reg)
  float4 b4 = *(const float4*)&bias[cb];
  int2 tr2 = *(const int2*)&tree[cb >> 1]; // tree[j0], tree[j0+1]
  float bb[4] = { b4.x, b4.y, b4.z, b4.w };
  int tt[2] = { tr2.x, tr2.y };
  ushort8 v;
#pragma unroll
  for (int p = 0; p < 2; ++p) {
    float l1 = acc[2 * p + 1] + bb[2 * p + 1];
    float l0 = (tt[p] == -1) ? l1 : (acc[2 * p] + bb[2 * p]);
    // logsig(v) = v>=0 ? -log(1+e^-v) : v - log(1+e^v);  logsig(-v) = logsig(v) - v
    float e0 = __expf(-fabsf(l0)); float sp0 = __logf(1.f + e0);
    float ls0 = (l0 >= 0.f) ? -sp0 : l0 - sp0;
    float e1 = __expf(-fabsf(l1)); float sp1 = __logf(1.f + e1);
    float ls1 = (l1 >= 0.f) ? -sp1 : l1 - sp1;
    v[4 * p + 0] = f2bf(ls0);
    v[4 * p + 1] = f2bf(ls1);
    v[4 * p + 2] = f2bf(ls0 - l0);
    v[4 * p + 3] = f2bf(ls1 - l1);
  }
  *(ushort8*)&Bmat[(size_t)row * KDIM + cb * 2] = v;   // 16B, aligned (cb%4==0)
}

// ---------------- Kernel 3: GEMM out[b,i] += A[256xK] . B[4096xK]^T ----------------
// Tile 256m x 64n (ONE m-pass: Bmat read exactly once), BK=32, 8-way K-split.
// 4 waves, each 64m x 64n = 16 MFMA per step. LDS pitch 40 shorts -> 2-way (free).
#define LP 40
__global__ __launch_bounds__(256) void gemm2(const unsigned short* __restrict__ Amat,
                                             const unsigned short* __restrict__ Bmat,
                                             float* __restrict__ out) {
  __shared__ unsigned short As[256][LP];   // 20480 B
  __shared__ unsigned short Bs[64][LP];    //  5120 B
  int bid = blockIdx.x;                    // 512 = 64 n-tiles x 8 k-splits
  int s = bid & 7, nt = bid >> 3;
  int n0 = nt * 64;
  int kt0 = s * 12 + (s < 2 ? s : 2);      // 98 = 13+13+12*6
  int nsteps = (s < 2) ? 13 : 12;
  int tid = threadIdx.x;
  int w = tid >> 6, lane = tid & 63;
  int srow = tid >> 2, scol = (tid & 3) * 8;
  const unsigned short* Ag = Amat + (size_t)srow * KDIM + scol;
  const unsigned short* Bg = Bmat + (size_t)(n0 + srow) * KDIM + scol;
  int fr = lane & 15, kq = (lane >> 4) * 8;

  f32x4 acc[4][4];
#pragma unroll
  for (int m = 0; m < 4; ++m)
#pragma unroll
    for (int n = 0; n < 4; ++n) acc[m][n] = (f32x4){0.f, 0.f, 0.f, 0.f};

  for (int kt = kt0; kt < kt0 + nsteps; ++kt) {
    int k0 = kt * 32;
#pragma unroll
    for (int q = 0; q < 4; ++q)
      *(float4*)&As[srow + q * 64][scol] = *(const float4*)(Ag + (size_t)q * 64 * KDIM + k0);
    *(float4*)&Bs[srow][scol] = *(const float4*)(Bg + k0);
    __syncthreads();
    bf16x8 a[4], b[4];
#pragma unroll
    for (int m = 0; m < 4; ++m) a[m] = *(const bf16x8*)&As[w * 64 + m * 16 + fr][kq];
#pragma unroll
    for (int n = 0; n < 4; ++n) b[n] = *(const bf16x8*)&Bs[n * 16 + fr][kq];
#pragma unroll
    for (int m = 0; m < 4; ++m)
#pragma unroll
      for (int n = 0; n < 4; ++n)
        acc[m][n] = __builtin_amdgcn_mfma_f32_16x16x32_bf16(a[m], b[n], acc[m][n], 0, 0, 0);
    __syncthreads();
  }
  // C/D: col = lane&15 (n), row = (lane>>4)*4 + reg (m)
  int col = lane & 15, rq = (lane >> 4) * 4;
#pragma unroll
  for (int m = 0; m < 4; ++m)
#pragma unroll
    for (int n = 0; n < 4; ++n)
#pragma unroll
      for (int r = 0; r < 4; ++r) {
        int mm = w * 64 + m * 16 + rq + r;
        int nn = n0 + n * 16 + col;
        atomicAdd(&out[(size_t)mm * BZN + nn], acc[m][n][r]);
      }
}

extern "C" void kernel_launch(void* const* d_in, const int* in_sizes, int n_in,
                              void* d_out, int out_size, void* d_ws, size_t ws_size,
                              hipStream_t stream) {
  const float* x    = (const float*)d_in[0];
  const float* z    = (const float*)d_in[1];
  const float* W    = (const float*)d_in[2];
  const float* bias = (const float*)d_in[3];
  const int*   tree = (const int*)d_in[4];
  float* out = (float*)d_out;

  unsigned short* Amat = (unsigned short*)d_ws;                        // 1,605,632 B
  unsigned short* Bmat = (unsigned short*)((char*)d_ws + 1605632);     // 25,690,112 B
  unsigned short* zb   = (unsigned short*)((char*)d_ws + 27295744);    //   524,288 B
  unsigned short* Wt   = (unsigned short*)((char*)d_ws + 27820032);    //   200,704 B

  prep<<<dim3(2402), 256, 0, stream>>>(x, z, W, tree, Amat, zb, Wt, out);
  build_b<<<dim3(6272), 256, 0, stream>>>(zb, Wt, bias, tree, Bmat);
  gemm2<<<dim3(512), 256, 0, stream>>>(Amat, Bmat, out);
}

// Round 4
// 52.018 us; speedup vs baseline: 1.8117x; 1.2868x over previous
//
#include <hip/hip_runtime.h>

#define NF   784
#define ZD   64
#define BXN  256
#define BZN  4096
#define KDIM 3136    // 4*NF
#define LCOL 1568    // 2*NF logit columns

typedef __attribute__((ext_vector_type(8))) short bf16x8;
typedef __attribute__((ext_vector_type(4))) float f32x4;
typedef __attribute__((ext_vector_type(8))) unsigned short ushort8;

__device__ __forceinline__ unsigned short f2bf(float f) {
  unsigned u = __float_as_uint(f);
  u += 0x7fff + ((u >> 16) & 1);   // round-to-nearest-even
  return (unsigned short)(u >> 16);
}

// ---------------- Kernel 1: prep (fused) ----------------
// blocks [0,1024):     build A-matrix (256 x 3136 bf16)
// blocks [1024,1280):  z (4096x64 f32) -> zb bf16
// blocks [1280,1378):  W (64x1568 f32) -> Wt (1568x64 bf16, transposed)
__global__ __launch_bounds__(256) void prep(const float* __restrict__ x,
                                            const float* __restrict__ z,
                                            const float* __restrict__ W,
                                            const int* __restrict__ tree,
                                            unsigned short* __restrict__ Amat,
                                            unsigned short* __restrict__ zb,
                                            unsigned short* __restrict__ Wt) {
  int bid = blockIdx.x, tid = threadIdx.x;
  if (bid < 1024) {                       // ---- build_a
    int b = bid >> 2;
    int j = (bid & 3) * 256 + tid;
    if (j >= NF) return;
    float xb = x[b * NF + j];
    int idx = tree[j];
    int gidx = idx < 0 ? idx + NF : idx;  // JAX negative-index wrap
    float xt = x[b * NF + gidx];
    ushort4 v;
    v.x = f2bf((1.f - xt) * xb);
    v.y = f2bf(xt * xb);
    v.z = f2bf((1.f - xt) * (1.f - xb));
    v.w = f2bf(xt * (1.f - xb));
    *(ushort4*)&Amat[(size_t)b * KDIM + 4 * j] = v;
  } else if (bid < 1280) {                // ---- z -> bf16
    int t = (bid - 1024) * 256 + tid;     // 0..65535, 4 elems each
    float4 v = *(const float4*)&z[t * 4];
    ushort4 o = { f2bf(v.x), f2bf(v.y), f2bf(v.z), f2bf(v.w) };
    *(ushort4*)&zb[t * 4] = o;
  } else {                                // ---- W -> Wt (transpose)
    int t = (bid - 1280) * 256 + tid;     // 0..25087
    int c = t >> 4, k0 = (t & 15) * 4;    // c<1568, k0<64
    ushort4 o;
    o.x = f2bf(W[(k0 + 0) * LCOL + c]);
    o.y = f2bf(W[(k0 + 1) * LCOL + c]);
    o.z = f2bf(W[(k0 + 2) * LCOL + c]);
    o.w = f2bf(W[(k0 + 3) * LCOL + c]);
    *(ushort4*)&Wt[c * 64 + k0] = o;
  }
}

// ---------------- Kernel 2: logits via MFMA + log-sigmoid -> B-matrix ----------------
// D = Wt(M=1568 logit cols) x zb(N=4096 z rows), K=64 -> 2 MFMAs, no LDS.
// Lane layout: D col = lane&15 (z-row), D rows = (lane>>4)*4+reg (4 consecutive
// logit cols = two (l0,l1) pairs) -> lane-local epilogue, one 16B store.
__global__ __launch_bounds__(256) void build_b(const unsigned short* __restrict__ zb,
                                               const unsigned short* __restrict__ Wt,
                                               const float* __restrict__ bias,
                                               const int* __restrict__ tree,
                                               unsigned short* __restrict__ Bmat) {
  int tid = threadIdx.x;
  int w = tid >> 6, lane = tid & 63;
  int job = blockIdx.x * 4 + w;           // 25088 jobs = 256 i-groups x 98 c-groups
  int ig = job / 98;
  int cg = job - ig * 98;
  int i0 = ig * 16, c0 = cg * 16;
  int fr = lane & 15, kq = (lane >> 4) * 8;

  const unsigned short* WtP = Wt + (c0 + fr) * 64 + kq;
  const unsigned short* zbP = zb + (size_t)(i0 + fr) * 64 + kq;
  bf16x8 a0 = *(const bf16x8*)(WtP);
  bf16x8 a1 = *(const bf16x8*)(WtP + 32);
  bf16x8 b0 = *(const bf16x8*)(zbP);
  bf16x8 b1 = *(const bf16x8*)(zbP + 32);
  f32x4 acc = (f32x4){0.f, 0.f, 0.f, 0.f};
  acc = __builtin_amdgcn_mfma_f32_16x16x32_bf16(a0, b0, acc, 0, 0, 0);
  acc = __builtin_amdgcn_mfma_f32_16x16x32_bf16(a1, b1, acc, 0, 0, 0);

  int row = i0 + fr;                       // z-row (D col = lane&15)
  int cb = c0 + (lane >> 4) * 4;           // logit col base (D row = (lane>>4)*4+reg)
  float4 b4 = *(const float4*)&bias[cb];
  int2 tr2 = *(const int2*)&tree[cb >> 1]; // tree[j0], tree[j0+1]
  float bb[4] = { b4.x, b4.y, b4.z, b4.w };
  int tt[2] = { tr2.x, tr2.y };
  ushort8 v;
#pragma unroll
  for (int p = 0; p < 2; ++p) {
    float l1 = acc[2 * p + 1] + bb[2 * p + 1];
    float l0 = (tt[p] == -1) ? l1 : (acc[2 * p] + bb[2 * p]);
    // logsig(v) = v>=0 ? -log(1+e^-v) : v - log(1+e^v);  logsig(-v) = logsig(v) - v
    float e0 = __expf(-fabsf(l0)); float sp0 = __logf(1.f + e0);
    float ls0 = (l0 >= 0.f) ? -sp0 : l0 - sp0;
    float e1 = __expf(-fabsf(l1)); float sp1 = __logf(1.f + e1);
    float ls1 = (l1 >= 0.f) ? -sp1 : l1 - sp1;
    v[4 * p + 0] = f2bf(ls0);
    v[4 * p + 1] = f2bf(ls1);
    v[4 * p + 2] = f2bf(ls0 - l0);
    v[4 * p + 3] = f2bf(ls1 - l1);
  }
  *(ushort8*)&Bmat[(size_t)row * KDIM + cb * 2] = v;   // 16B, aligned (cb%4==0)
}

// ---------------- Kernel 3: GEMM partials (NO atomics) ----------------
// Tile 256m x 64n, BK=32, 8-way K-split. Each block writes its partial sums
// as plain f32 stores to part[s][256][4096]. 4 waves, 16 MFMA/step/wave.
#define LP 40
__global__ __launch_bounds__(256) void gemm2(const unsigned short* __restrict__ Amat,
                                             const unsigned short* __restrict__ Bmat,
                                             float* __restrict__ part) {
  __shared__ unsigned short As[256][LP];   // 20480 B
  __shared__ unsigned short Bs[64][LP];    //  5120 B
  int bid = blockIdx.x;                    // 512 = 64 n-tiles x 8 k-splits
  int s = bid & 7, nt = bid >> 3;
  int n0 = nt * 64;
  int kt0 = s * 12 + (s < 2 ? s : 2);      // 98 = 13+13+12*6
  int nsteps = (s < 2) ? 13 : 12;
  int tid = threadIdx.x;
  int w = tid >> 6, lane = tid & 63;
  int srow = tid >> 2, scol = (tid & 3) * 8;
  const unsigned short* Ag = Amat + (size_t)srow * KDIM + scol;
  const unsigned short* Bg = Bmat + (size_t)(n0 + srow) * KDIM + scol;
  int fr = lane & 15, kq = (lane >> 4) * 8;

  f32x4 acc[4][4];
#pragma unroll
  for (int m = 0; m < 4; ++m)
#pragma unroll
    for (int n = 0; n < 4; ++n) acc[m][n] = (f32x4){0.f, 0.f, 0.f, 0.f};

  for (int kt = kt0; kt < kt0 + nsteps; ++kt) {
    int k0 = kt * 32;
#pragma unroll
    for (int q = 0; q < 4; ++q)
      *(float4*)&As[srow + q * 64][scol] = *(const float4*)(Ag + (size_t)q * 64 * KDIM + k0);
    *(float4*)&Bs[srow][scol] = *(const float4*)(Bg + k0);
    __syncthreads();
    bf16x8 a[4], b[4];
#pragma unroll
    for (int m = 0; m < 4; ++m) a[m] = *(const bf16x8*)&As[w * 64 + m * 16 + fr][kq];
#pragma unroll
    for (int n = 0; n < 4; ++n) b[n] = *(const bf16x8*)&Bs[n * 16 + fr][kq];
#pragma unroll
    for (int m = 0; m < 4; ++m)
#pragma unroll
      for (int n = 0; n < 4; ++n)
        acc[m][n] = __builtin_amdgcn_mfma_f32_16x16x32_bf16(a[m], b[n], acc[m][n], 0, 0, 0);
    __syncthreads();
  }
  // C/D: col = lane&15 (n), row = (lane>>4)*4 + reg (m). Plain stores:
  // 16 lanes cover 64B contiguous per (m,r,n) -> coalesced 4x64B segments/instr.
  int col = lane & 15, rq = (lane >> 4) * 4;
  float* Pp = part + (size_t)s * (256 * 4096) + (size_t)(w * 64) * 4096 + n0;
#pragma unroll
  for (int m = 0; m < 4; ++m)
#pragma unroll
    for (int n = 0; n < 4; ++n)
#pragma unroll
      for (int r = 0; r < 4; ++r)
        Pp[(m * 16 + rq + r) * 4096 + n * 16 + col] = acc[m][n][r];
}

// ---------------- Kernel 4: reduce 8 partials -> d_out ----------------
__global__ __launch_bounds__(256) void reduce8(const float* __restrict__ part,
                                               float* __restrict__ out) {
  int t = blockIdx.x * 256 + threadIdx.x;  // 262144 threads x float4
  f32x4 s = (f32x4){0.f, 0.f, 0.f, 0.f};
#pragma unroll
  for (int q = 0; q < 8; ++q)
    s += *(const f32x4*)&part[(size_t)q * (256 * 4096) + (size_t)t * 4];
  *(f32x4*)&out[(size_t)t * 4] = s;
}

extern "C" void kernel_launch(void* const* d_in, const int* in_sizes, int n_in,
                              void* d_out, int out_size, void* d_ws, size_t ws_size,
                              hipStream_t stream) {
  const float* x    = (const float*)d_in[0];
  const float* z    = (const float*)d_in[1];
  const float* W    = (const float*)d_in[2];
  const float* bias = (const float*)d_in[3];
  const int*   tree = (const int*)d_in[4];
  float* out = (float*)d_out;

  unsigned short* Amat = (unsigned short*)d_ws;                        // 1,605,632 B
  unsigned short* Bmat = (unsigned short*)((char*)d_ws + 1605632);     // 25,690,112 B
  unsigned short* zb   = (unsigned short*)((char*)d_ws + 27295744);    //   524,288 B
  unsigned short* Wt   = (unsigned short*)((char*)d_ws + 27820032);    //   200,704 B
  float*          part = (float*)((char*)d_ws + 28020736);             // 33,554,432 B

  prep<<<dim3(1378), 256, 0, stream>>>(x, z, W, tree, Amat, zb, Wt);
  build_b<<<dim3(6272), 256, 0, stream>>>(zb, Wt, bias, tree, Bmat);
  gemm2<<<dim3(512), 256, 0, stream>>>(Amat, Bmat, part);
  reduce8<<<dim3(1024), 256, 0, stream>>>(part, out);
}

// Round 5
// 44.739 us; speedup vs baseline: 2.1065x; 1.1627x over previous
//
#include <hip/hip_runtime.h>

#define NF   784
#define ZD   64
#define BXN  256
#define BZN  4096
#define KDIM 3136    // 4*NF
#define LCOL 1568    // 2*NF logit columns

typedef __attribute__((ext_vector_type(8))) short bf16x8;
typedef __attribute__((ext_vector_type(4))) float f32x4;
typedef __attribute__((ext_vector_type(8))) unsigned short ushort8;

__device__ __forceinline__ unsigned short f2bf(float f) {
  unsigned u = __float_as_uint(f);
  u += 0x7fff + ((u >> 16) & 1);   // round-to-nearest-even
  return (unsigned short)(u >> 16);
}

// ---------------- Kernel 1: prep (fused) ----------------
// blocks [0,1024):     build A-matrix (256 x 3136 bf16)
// blocks [1024,1280):  z (4096x64 f32) -> zb bf16
// blocks [1280,1378):  W (64x1568 f32) -> Wt (1568x64 bf16, transposed)
__global__ __launch_bounds__(256) void prep(const float* __restrict__ x,
                                            const float* __restrict__ z,
                                            const float* __restrict__ W,
                                            const int* __restrict__ tree,
                                            unsigned short* __restrict__ Amat,
                                            unsigned short* __restrict__ zb,
                                            unsigned short* __restrict__ Wt) {
  int bid = blockIdx.x, tid = threadIdx.x;
  if (bid < 1024) {                       // ---- build_a
    int b = bid >> 2;
    int j = (bid & 3) * 256 + tid;
    if (j >= NF) return;
    float xb = x[b * NF + j];
    int idx = tree[j];
    int gidx = idx < 0 ? idx + NF : idx;  // JAX negative-index wrap
    float xt = x[b * NF + gidx];
    ushort4 v;
    v.x = f2bf((1.f - xt) * xb);
    v.y = f2bf(xt * xb);
    v.z = f2bf((1.f - xt) * (1.f - xb));
    v.w = f2bf(xt * (1.f - xb));
    *(ushort4*)&Amat[(size_t)b * KDIM + 4 * j] = v;
  } else if (bid < 1280) {                // ---- z -> bf16
    int t = (bid - 1024) * 256 + tid;     // 0..65535, 4 elems each
    float4 v = *(const float4*)&z[t * 4];
    ushort4 o = { f2bf(v.x), f2bf(v.y), f2bf(v.z), f2bf(v.w) };
    *(ushort4*)&zb[t * 4] = o;
  } else {                                // ---- W -> Wt (transpose)
    int t = (bid - 1280) * 256 + tid;     // 0..25087
    int c = t >> 4, k0 = (t & 15) * 4;    // c<1568, k0<64
    ushort4 o;
    o.x = f2bf(W[(k0 + 0) * LCOL + c]);
    o.y = f2bf(W[(k0 + 1) * LCOL + c]);
    o.z = f2bf(W[(k0 + 2) * LCOL + c]);
    o.w = f2bf(W[(k0 + 3) * LCOL + c]);
    *(ushort4*)&Wt[c * 64 + k0] = o;
  }
}

// ---------------- Kernel 2: FUSED logits+logsigmoid+GEMM ----------------
// out partials: part[s][256 b][4096 i], no Bmat intermediate.
// Per step (32 K = 8 features = 16 logit cols):
//   1. A-tile global->reg (T14 issue-early)
//   2. logits for this step's 16 cols x this wave's 16 z-rows: 2 MFMA
//      (z fragments register-resident across all steps)
//   3. log-sigmoid epilogue in-register (build_b's verified lane layout)
//   4. ds_write A regs + B ushort8 -> LDS, sync
//   5. main MFMA: 16 per wave, sync
#define LP 40
__global__ __launch_bounds__(256) void gemm_fused(const unsigned short* __restrict__ Amat,
                                                  const unsigned short* __restrict__ zb,
                                                  const unsigned short* __restrict__ Wt,
                                                  const float* __restrict__ bias,
                                                  const int* __restrict__ tree,
                                                  float* __restrict__ part) {
  __shared__ unsigned short As[256][LP];   // 20480 B
  __shared__ unsigned short Bs[64][LP];    //  5120 B
  int bid = blockIdx.x;                    // 512 = 64 n-tiles x 8 k-splits
  int s = bid & 7, nt = bid >> 3;
  int n0 = nt * 64;
  int kt0 = s * 12 + (s < 2 ? s : 2);      // 98 = 13+13+12*6
  int nsteps = (s < 2) ? 13 : 12;
  int tid = threadIdx.x;
  int w = tid >> 6, lane = tid & 63;
  int fr = lane & 15, hi = lane >> 4, kq = hi * 8;
  int srow = tid >> 2, scol = (tid & 3) * 8;
  const unsigned short* Ag = Amat + (size_t)srow * KDIM + scol;

  // z fragments: this wave's 16 z-rows, both K=32 halves. Resident all steps.
  const unsigned short* zp = zb + (size_t)(n0 + w * 16 + fr) * 64 + kq;
  bf16x8 zf0 = *(const bf16x8*)zp;
  bf16x8 zf1 = *(const bf16x8*)(zp + 32);

  f32x4 acc[4][4];
#pragma unroll
  for (int m = 0; m < 4; ++m)
#pragma unroll
    for (int n = 0; n < 4; ++n) acc[m][n] = (f32x4){0.f, 0.f, 0.f, 0.f};

  for (int kt = kt0; kt < kt0 + nsteps; ++kt) {
    int k0 = kt * 32;
    // --- 1. A-tile loads issue early (latency hides under logits phase)
    float4 ar[4];
#pragma unroll
    for (int q = 0; q < 4; ++q)
      ar[q] = *(const float4*)(Ag + (size_t)q * 64 * KDIM + k0);
    // --- 2. logits MFMA: M=16 logit cols (16kt..16kt+15), N=16 z-rows
    const unsigned short* wp = Wt + (size_t)(kt * 16 + fr) * 64 + kq;
    bf16x8 wf0 = *(const bf16x8*)wp;
    bf16x8 wf1 = *(const bf16x8*)(wp + 32);
    f32x4 lacc = (f32x4){0.f, 0.f, 0.f, 0.f};
    lacc = __builtin_amdgcn_mfma_f32_16x16x32_bf16(wf0, zf0, lacc, 0, 0, 0);
    lacc = __builtin_amdgcn_mfma_f32_16x16x32_bf16(wf1, zf1, lacc, 0, 0, 0);
    // --- 3. log-sigmoid epilogue: lane holds logit cols 16kt+4hi+{0..3}
    //        for z-row n0+16w+fr = features 8kt+2hi+{0,1}
    float4 b4 = *(const float4*)&bias[kt * 16 + 4 * hi];
    int2 tr2 = *(const int2*)&tree[kt * 8 + 2 * hi];
    float bb[4] = { b4.x, b4.y, b4.z, b4.w };
    int tt[2] = { tr2.x, tr2.y };
    ushort8 v;
#pragma unroll
    for (int p = 0; p < 2; ++p) {
      float l1 = lacc[2 * p + 1] + bb[2 * p + 1];
      float l0 = (tt[p] == -1) ? l1 : (lacc[2 * p] + bb[2 * p]);
      float e0 = __expf(-fabsf(l0)); float sp0 = __logf(1.f + e0);
      float ls0 = (l0 >= 0.f) ? -sp0 : l0 - sp0;
      float e1 = __expf(-fabsf(l1)); float sp1 = __logf(1.f + e1);
      float ls1 = (l1 >= 0.f) ? -sp1 : l1 - sp1;
      v[4 * p + 0] = f2bf(ls0);
      v[4 * p + 1] = f2bf(ls1);
      v[4 * p + 2] = f2bf(ls0 - l0);
      v[4 * p + 3] = f2bf(ls1 - l1);
    }
    // --- 4. stage to LDS
#pragma unroll
    for (int q = 0; q < 4; ++q)
      *(float4*)&As[srow + q * 64][scol] = ar[q];
    *(ushort8*)&Bs[w * 16 + fr][kq] = v;   // K-slots 8hi..8hi+7 == global k0+8hi.. ✓
    __syncthreads();
    // --- 5. main MFMA
    bf16x8 a[4], b[4];
#pragma unroll
    for (int m = 0; m < 4; ++m) a[m] = *(const bf16x8*)&As[w * 64 + m * 16 + fr][kq];
#pragma unroll
    for (int n = 0; n < 4; ++n) b[n] = *(const bf16x8*)&Bs[n * 16 + fr][kq];
#pragma unroll
    for (int m = 0; m < 4; ++m)
#pragma unroll
      for (int n = 0; n < 4; ++n)
        acc[m][n] = __builtin_amdgcn_mfma_f32_16x16x32_bf16(a[m], b[n], acc[m][n], 0, 0, 0);
    __syncthreads();
  }
  // C/D: col = lane&15 (n), row = (lane>>4)*4 + reg (m). Plain coalesced stores.
  int col = lane & 15, rq = hi * 4;
  float* Pp = part + (size_t)s * (256 * 4096) + (size_t)(w * 64) * 4096 + n0;
#pragma unroll
  for (int m = 0; m < 4; ++m)
#pragma unroll
    for (int n = 0; n < 4; ++n)
#pragma unroll
      for (int r = 0; r < 4; ++r)
        Pp[(m * 16 + rq + r) * 4096 + n * 16 + col] = acc[m][n][r];
}

// ---------------- Kernel 3: reduce 8 partials -> d_out ----------------
__global__ __launch_bounds__(256) void reduce8(const float* __restrict__ part,
                                               float* __restrict__ out) {
  int t = blockIdx.x * 256 + threadIdx.x;  // 262144 threads x float4
  f32x4 s = (f32x4){0.f, 0.f, 0.f, 0.f};
#pragma unroll
  for (int q = 0; q < 8; ++q)
    s += *(const f32x4*)&part[(size_t)q * (256 * 4096) + (size_t)t * 4];
  *(f32x4*)&out[(size_t)t * 4] = s;
}

extern "C" void kernel_launch(void* const* d_in, const int* in_sizes, int n_in,
                              void* d_out, int out_size, void* d_ws, size_t ws_size,
                              hipStream_t stream) {
  const float* x    = (const float*)d_in[0];
  const float* z    = (const float*)d_in[1];
  const float* W    = (const float*)d_in[2];
  const float* bias = (const float*)d_in[3];
  const int*   tree = (const int*)d_in[4];
  float* out = (float*)d_out;

  unsigned short* Amat = (unsigned short*)d_ws;                     // 1,605,632 B
  unsigned short* zb   = (unsigned short*)((char*)d_ws + 1605632);  //   524,288 B
  unsigned short* Wt   = (unsigned short*)((char*)d_ws + 2129920);  //   200,704 B
  float*          part = (float*)((char*)d_ws + 2330624);           // 33,554,432 B

  prep<<<dim3(1378), 256, 0, stream>>>(x, z, W, tree, Amat, zb, Wt);
  gemm_fused<<<dim3(512), 256, 0, stream>>>(Amat, zb, Wt, bias, tree, part);
  reduce8<<<dim3(1024), 256, 0, stream>>>(part, out);
}

// Round 6
// 44.198 us; speedup vs baseline: 2.1323x; 1.0123x over previous
//
#include <hip/hip_runtime.h>

#define NF   784
#define ZD   64
#define BXN  256
#define BZN  4096
#define KDIM 3136    // 4*NF
#define LCOL 1568    // 2*NF logit columns

typedef __attribute__((ext_vector_type(8))) short bf16x8;
typedef __attribute__((ext_vector_type(4))) float f32x4;
typedef __attribute__((ext_vector_type(8))) unsigned short ushort8;

__device__ __forceinline__ unsigned short f2bf(float f) {
  unsigned u = __float_as_uint(f);
  u += 0x7fff + ((u >> 16) & 1);   // round-to-nearest-even
  return (unsigned short)(u >> 16);
}

// ---------------- Kernel 1: prep (fused) ----------------
__global__ __launch_bounds__(256) void prep(const float* __restrict__ x,
                                            const float* __restrict__ z,
                                            const float* __restrict__ W,
                                            const int* __restrict__ tree,
                                            unsigned short* __restrict__ Amat,
                                            unsigned short* __restrict__ zb,
                                            unsigned short* __restrict__ Wt) {
  int bid = blockIdx.x, tid = threadIdx.x;
  if (bid < 1024) {                       // ---- build_a
    int b = bid >> 2;
    int j = (bid & 3) * 256 + tid;
    if (j >= NF) return;
    float xb = x[b * NF + j];
    int idx = tree[j];
    int gidx = idx < 0 ? idx + NF : idx;  // JAX negative-index wrap
    float xt = x[b * NF + gidx];
    ushort4 v;
    v.x = f2bf((1.f - xt) * xb);
    v.y = f2bf(xt * xb);
    v.z = f2bf((1.f - xt) * (1.f - xb));
    v.w = f2bf(xt * (1.f - xb));
    *(ushort4*)&Amat[(size_t)b * KDIM + 4 * j] = v;
  } else if (bid < 1280) {                // ---- z -> bf16
    int t = (bid - 1024) * 256 + tid;
    float4 v = *(const float4*)&z[t * 4];
    ushort4 o = { f2bf(v.x), f2bf(v.y), f2bf(v.z), f2bf(v.w) };
    *(ushort4*)&zb[t * 4] = o;
  } else {                                // ---- W -> Wt (transpose)
    int t = (bid - 1280) * 256 + tid;
    int c = t >> 4, k0 = (t & 15) * 4;
    ushort4 o;
    o.x = f2bf(W[(k0 + 0) * LCOL + c]);
    o.y = f2bf(W[(k0 + 1) * LCOL + c]);
    o.z = f2bf(W[(k0 + 2) * LCOL + c]);
    o.w = f2bf(W[(k0 + 3) * LCOL + c]);
    *(ushort4*)&Wt[c * 64 + k0] = o;
  }
}

// ---------------- Kernel 2: FUSED logits+logsigmoid+GEMM, pipelined ----------------
// Per step: logit MFMA (regs prefetched LAST step) -> issue next-step loads ->
// logsig -> stage to LDS[buf] -> ONE barrier -> main MFMA. LDS double-buffered.
#define LP 40
__global__ __launch_bounds__(256) void gemm_fused(const unsigned short* __restrict__ Amat,
                                                  const unsigned short* __restrict__ zb,
                                                  const unsigned short* __restrict__ Wt,
                                                  const float* __restrict__ bias,
                                                  const int* __restrict__ tree,
                                                  float* __restrict__ part) {
  __shared__ unsigned short As[2][256][LP];  // 40960 B
  __shared__ unsigned short Bs[2][64][LP];   // 10240 B
  int bid = blockIdx.x;                      // 512 = 64 n-tiles x 8 k-splits
  int s = bid & 7, nt = bid >> 3;
  int n0 = nt * 64;
  int kt0 = s * 12 + (s < 2 ? s : 2);        // 98 = 13+13+12*6
  int nsteps = (s < 2) ? 13 : 12;
  int ktend = kt0 + nsteps;
  int tid = threadIdx.x;
  int w = tid >> 6, lane = tid & 63;
  int fr = lane & 15, hi = lane >> 4, kq = hi * 8;
  int srow = tid >> 2, scol = (tid & 3) * 8;
  const unsigned short* Ag = Amat + (size_t)srow * KDIM + scol;

  // z fragments: this wave's 16 z-rows, register-resident across all steps.
  const unsigned short* zp = zb + (size_t)(n0 + w * 16 + fr) * 64 + kq;
  bf16x8 zf0 = *(const bf16x8*)zp;
  bf16x8 zf1 = *(const bf16x8*)(zp + 32);

  f32x4 acc[4][4];
#pragma unroll
  for (int m = 0; m < 4; ++m)
#pragma unroll
    for (int n = 0; n < 4; ++n) acc[m][n] = (f32x4){0.f, 0.f, 0.f, 0.f};

  // ---- prologue: load step kt0's registers
  const unsigned short* wp = Wt + (size_t)(kt0 * 16 + fr) * 64 + kq;
  bf16x8 wf0 = *(const bf16x8*)wp;
  bf16x8 wf1 = *(const bf16x8*)(wp + 32);
  float4 b4  = *(const float4*)&bias[kt0 * 16 + 4 * hi];
  int2   tr2 = *(const int2*)&tree[kt0 * 8 + 2 * hi];
  int k0 = kt0 * 32;
  float4 ar0 = *(const float4*)(Ag + k0);
  float4 ar1 = *(const float4*)(Ag + (size_t)64 * KDIM + k0);
  float4 ar2 = *(const float4*)(Ag + (size_t)128 * KDIM + k0);
  float4 ar3 = *(const float4*)(Ag + (size_t)192 * KDIM + k0);

  int buf = 0;
  for (int i = 0; i < nsteps; ++i) {
    int kt = kt0 + i;
    // --- 1. logit MFMA for current step (operands already in regs)
    f32x4 lacc = (f32x4){0.f, 0.f, 0.f, 0.f};
    lacc = __builtin_amdgcn_mfma_f32_16x16x32_bf16(wf0, zf0, lacc, 0, 0, 0);
    lacc = __builtin_amdgcn_mfma_f32_16x16x32_bf16(wf1, zf1, lacc, 0, 0, 0);
    // --- 2. prefetch step kt+1 (clamped on last iter; values unused then)
    int ktn = (kt + 1 < ktend) ? kt + 1 : kt;
    const unsigned short* wpn = Wt + (size_t)(ktn * 16 + fr) * 64 + kq;
    bf16x8 wfn0 = *(const bf16x8*)wpn;
    bf16x8 wfn1 = *(const bf16x8*)(wpn + 32);
    float4 b4n  = *(const float4*)&bias[ktn * 16 + 4 * hi];
    int2   tr2n = *(const int2*)&tree[ktn * 8 + 2 * hi];
    int k0n = ktn * 32;
    float4 arn0 = *(const float4*)(Ag + k0n);
    float4 arn1 = *(const float4*)(Ag + (size_t)64 * KDIM + k0n);
    float4 arn2 = *(const float4*)(Ag + (size_t)128 * KDIM + k0n);
    float4 arn3 = *(const float4*)(Ag + (size_t)192 * KDIM + k0n);
    // --- 3. log-sigmoid epilogue (hides prefetch latency)
    float bb[4] = { b4.x, b4.y, b4.z, b4.w };
    int tt[2] = { tr2.x, tr2.y };
    ushort8 v;
#pragma unroll
    for (int p = 0; p < 2; ++p) {
      float l1 = lacc[2 * p + 1] + bb[2 * p + 1];
      float l0 = (tt[p] == -1) ? l1 : (lacc[2 * p] + bb[2 * p]);
      float e0 = __expf(-fabsf(l0)); float sp0 = __logf(1.f + e0);
      float ls0 = (l0 >= 0.f) ? -sp0 : l0 - sp0;
      float e1 = __expf(-fabsf(l1)); float sp1 = __logf(1.f + e1);
      float ls1 = (l1 >= 0.f) ? -sp1 : l1 - sp1;
      v[4 * p + 0] = f2bf(ls0);
      v[4 * p + 1] = f2bf(ls1);
      v[4 * p + 2] = f2bf(ls0 - l0);
      v[4 * p + 3] = f2bf(ls1 - l1);
    }
    // --- 4. stage current step to LDS[buf]
    *(float4*)&As[buf][srow      ][scol] = ar0;
    *(float4*)&As[buf][srow +  64][scol] = ar1;
    *(float4*)&As[buf][srow + 128][scol] = ar2;
    *(float4*)&As[buf][srow + 192][scol] = ar3;
    *(ushort8*)&Bs[buf][w * 16 + fr][kq] = v;
    __syncthreads();          // single barrier: dbuf makes write(k+1) race-free
    // --- 5. main MFMA
    bf16x8 a[4], b[4];
#pragma unroll
    for (int m = 0; m < 4; ++m) a[m] = *(const bf16x8*)&As[buf][w * 64 + m * 16 + fr][kq];
#pragma unroll
    for (int n = 0; n < 4; ++n) b[n] = *(const bf16x8*)&Bs[buf][n * 16 + fr][kq];
#pragma unroll
    for (int m = 0; m < 4; ++m)
#pragma unroll
      for (int n = 0; n < 4; ++n)
        acc[m][n] = __builtin_amdgcn_mfma_f32_16x16x32_bf16(a[m], b[n], acc[m][n], 0, 0, 0);
    // --- 6. rotate pipeline registers
    wf0 = wfn0; wf1 = wfn1; b4 = b4n; tr2 = tr2n;
    ar0 = arn0; ar1 = arn1; ar2 = arn2; ar3 = arn3;
    buf ^= 1;
  }
  // C/D: col = lane&15 (n), row = (lane>>4)*4 + reg (m). Plain coalesced stores.
  int col = lane & 15, rq = hi * 4;
  float* Pp = part + (size_t)s * (256 * 4096) + (size_t)(w * 64) * 4096 + n0;
#pragma unroll
  for (int m = 0; m < 4; ++m)
#pragma unroll
    for (int n = 0; n < 4; ++n)
#pragma unroll
      for (int r = 0; r < 4; ++r)
        Pp[(m * 16 + rq + r) * 4096 + n * 16 + col] = acc[m][n][r];
}

// ---------------- Kernel 3: reduce 8 partials -> d_out ----------------
__global__ __launch_bounds__(256) void reduce8(const float* __restrict__ part,
                                               float* __restrict__ out) {
  int t = blockIdx.x * 256 + threadIdx.x;  // 262144 threads x float4
  f32x4 s = (f32x4){0.f, 0.f, 0.f, 0.f};
#pragma unroll
  for (int q = 0; q < 8; ++q)
    s += *(const f32x4*)&part[(size_t)q * (256 * 4096) + (size_t)t * 4];
  *(f32x4*)&out[(size_t)t * 4] = s;
}

extern "C" void kernel_launch(void* const* d_in, const int* in_sizes, int n_in,
                              void* d_out, int out_size, void* d_ws, size_t ws_size,
                              hipStream_t stream) {
  const float* x    = (const float*)d_in[0];
  const float* z    = (const float*)d_in[1];
  const float* W    = (const float*)d_in[2];
  const float* bias = (const float*)d_in[3];
  const int*   tree = (const int*)d_in[4];
  float* out = (float*)d_out;

  unsigned short* Amat = (unsigned short*)d_ws;                     // 1,605,632 B
  unsigned short* zb   = (unsigned short*)((char*)d_ws + 1605632);  //   524,288 B
  unsigned short* Wt   = (unsigned short*)((char*)d_ws + 2129920);  //   200,704 B
  float*          part = (float*)((char*)d_ws + 2330624);           // 33,554,432 B

  prep<<<dim3(1378), 256, 0, stream>>>(x, z, W, tree, Amat, zb, Wt);
  gemm_fused<<<dim3(512), 256, 0, stream>>>(Amat, zb, Wt, bias, tree, part);
  reduce8<<<dim3(1024), 256, 0, stream>>>(part, out);
}